// Round 8
// baseline (183.150 us; speedup 1.0000x reference)
//
#include <hip/hip_runtime.h>
#include <hip/hip_bf16.h>

#define BD 8
#define LD 2048
#define DD 256

typedef unsigned short ushort_t;
typedef __attribute__((ext_vector_type(8))) short short8;
typedef __attribute__((ext_vector_type(4))) float floatx4;

__device__ __forceinline__ ushort_t f2bfu(float x) {
  __hip_bfloat16 h = __float2bfloat16(x);
  return *reinterpret_cast<ushort_t*>(&h);
}

// async global->LDS DMA, 16 B per lane; LDS dest = wave-uniform base + lane*16
__device__ __forceinline__ void dma16(const ushort_t* g, ushort_t* l) {
  __builtin_amdgcn_global_load_lds(
      (const __attribute__((address_space(1))) unsigned int*)g,
      (__attribute__((address_space(3))) unsigned int*)l,
      16, 0, 0);
}

// accurate sin/cos for args up to ~200 rad: one Cody-Waite step, then hw trig
__device__ __forceinline__ float sin_acc(float a) {
  float k = rintf(a * 0.15915494f);
  float r = __builtin_fmaf(-k, 6.2831855f, a);
  r = __builtin_fmaf(-k, -1.7484555e-7f, r);
  return __sinf(r);
}
__device__ __forceinline__ float cos_acc(float a) {
  float k = rintf(a * 0.15915494f);
  float r = __builtin_fmaf(-k, 6.2831855f, a);
  r = __builtin_fmaf(-k, -1.7484555e-7f, r);
  return __cosf(r);
}

// ---------------- Kernel 1: FUSED prep (cast + enc + per-type dots) ----------------
// blocks [0,4224): bf16 cast of noise + concat weights
// blocks [4224,4736): temporal encoding -> enc_bf (B-frag-native layout)
// block 4736: the 2 per-type parameter triples
__global__ __launch_bounds__(256) void k_prep(
    const int* __restrict__ etype, const float* __restrict__ etime,
    const float* __restrict__ embw, const float* __restrict__ gatew,
    const float* __restrict__ gateb, const float* __restrict__ kerw,
    const float* __restrict__ kerb, const float* __restrict__ noise,
    const float* __restrict__ wn, const float* __restrict__ wi,
    ushort_t* __restrict__ enc_bf, ushort_t* __restrict__ noise_bf,
    ushort_t* __restrict__ wcat, float* __restrict__ ptable)
{
  const int bk = blockIdx.x;
  const int tid = threadIdx.x;
  if (bk < 4224) {                           // ---- cast ----
    int idx = bk * 256 + tid;                // float4 index
    if (idx < 1048576) {
      float4 f = ((const float4*)noise)[idx];
      ushort4 u;
      u.x = f2bfu(f.x); u.y = f2bfu(f.y); u.z = f2bfu(f.z); u.w = f2bfu(f.w);
      *(ushort4*)(noise_bf + (size_t)idx * 4) = u;
    } else {
      int p = idx - 1048576;                 // 0..32767
      int c = p >> 7;
      int k = (p & 127) * 4;
      const float* src = (k < 256) ? (wn + c * 256 + k) : (wi + c * 256 + (k - 256));
      float4 f = *(const float4*)src;
      ushort4 u;
      u.x = f2bfu(f.x); u.y = f2bfu(f.y); u.z = f2bfu(f.z); u.w = f2bfu(f.w);
      *(ushort4*)(wcat + (size_t)c * 512 + k) = u;
    }
  } else if (bk < 4736) {                    // ---- enc ----
    int ebk = bk - 4224;                     // 0..511 : b = ebk>>6, ch = ebk&63
    __shared__ float ts[32];
    if (tid < 32) ts[tid] = etime[(ebk >> 6) * LD + (ebk & 63) * 32 + tid];
    __syncthreads();
    uint4* dst = (uint4*)(enc_bf + (size_t)ebk * 8192);
    const int jb = (tid & 3) * 8;
    #pragma unroll
    for (int jblk = 0; jblk < 4; ++jblk) {
      int d = jblk * 64 + (tid >> 2);
      float freq = __expf(-0.07195578416f * (float)d);   // 10000^(-2d/256)
      unsigned int pk[4];
      #pragma unroll
      for (int p = 0; p < 4; ++p) {
        float a0 = ts[jb + 2 * p] * freq;
        float a1 = ts[jb + 2 * p + 1] * freq;
        float v0 = (d & 1) ? cos_acc(a0) : sin_acc(a0);
        float v1 = (d & 1) ? cos_acc(a1) : sin_acc(a1);
        pk[p] = (unsigned int)f2bfu(v0) | ((unsigned int)f2bfu(v1) << 16);
      }
      dst[jblk * 256 + tid] = make_uint4(pk[0], pk[1], pk[2], pk[3]);
    }
  } else {                                   // ---- dots ----
    __shared__ float red[4][3];
    int lane = tid & 63, wvi = tid >> 6;
    for (int ty = 0; ty < 2; ++ty) {
      float te = embw[ty * DD + tid] * 16.0f;   // * sqrt(256)
      float p1 = te * kerw[tid];
      float p2 = te * gatew[tid];
      float p3 = te * gatew[DD + tid];
      #pragma unroll
      for (int off = 32; off > 0; off >>= 1) {
        p1 += __shfl_xor(p1, off);
        p2 += __shfl_xor(p2, off);
        p3 += __shfl_xor(p3, off);
      }
      if (lane == 0) { red[wvi][0] = p1; red[wvi][1] = p2; red[wvi][2] = p3; }
      __syncthreads();
      if (tid == 0) {
        float s1 = red[0][0] + red[1][0] + red[2][0] + red[3][0] + kerb[0];
        float s2 = red[0][1] + red[1][1] + red[2][1] + red[3][1] + gateb[0];
        float s3 = red[0][2] + red[1][2] + red[2][2] + red[3][2] + gateb[1];
        float z = 0.2f * s1;
        float sp = (z > 15.0f) ? z : log1pf(__expf(z));
        float ls = 5.0f * sp;                // softplus(0.2x)/0.2
        ptable[ty * 4 + 0] = 1.0f / (ls * ls);
        ptable[ty * 4 + 1] = 1.0f / (1.0f + __expf(-s2));
        float s = 1.0f / (1.0f + __expf(-s3));
        ptable[ty * 4 + 2] = 1.0f / s;
      }
      __syncthreads();
    }
  }
}

// ---------------- Kernel 2: MFMA causal gated attention + layernorm ----------------
// 512 blocks = 8 b x 64 row-blocks (32 rows = two 16-row tiles; both need rb+1 chunks).
// 4 waves: wv>>1 = tile, wv&1 = chunk parity owned (K-split). Every chunk is DMA'd
// ONCE into a shared 16 KB dbuf (each wave stages 4 frags) and consumed by both tiles.
// One __syncthreads per chunk = the DMA-complete wait; the in-flight DMA is always
// the NEXT chunk (issued after the barrier, overlapping MFMA + next weights).
__global__ __launch_bounds__(256, 4) void k_attn(
    const ushort_t* __restrict__ enc_bf, const float* __restrict__ etime,
    const int* __restrict__ etype, const float* __restrict__ ptable,
    const float* __restrict__ gamma, const float* __restrict__ beta,
    ushort_t* __restrict__ hidden_bf)
{
  __shared__ __align__(16) ushort_t stage[2][8192];   // 32 KB double buffer
  const int tid = threadIdx.x;
  const int lane = tid & 63, wv = tid >> 6;
  const int bk = blockIdx.x;
  const int b = bk & 7;                      // XCD-aligned batch locality
  const int rb = 63 - (bk >> 3);             // big row-blocks first
  const int base = b * LD;
  const int m = lane & 15, kg = lane >> 4;
  const int tile = 2 * rb + (wv >> 1);       // this wave's 16-row tile
  const int p = wv & 1;                      // chunk parity this wave owns
  const int i = tile * 16 + m;               // this lane's A-row
  const float ti = etime[base + i];
  const int ty = etype[base + i];
  const float il = ptable[ty * 4 + 0];
  const float ll = ptable[ty * 4 + 1];
  const float is2 = 2.0f * ptable[ty * 4 + 2];
  floatx4 acc[16];
  #pragma unroll
  for (int nt = 0; nt < 16; ++nt) acc[nt] = (floatx4){0.f, 0.f, 0.f, 0.f};
  const int nch = rb + 1;
  const ushort_t* __restrict__ encC = enc_bf + (size_t)(b * 64) * 8192;
  const int fr0 = wv * 4;                    // this wave's 4 DMA frags
  const int boff = m * 32 + kg * 8;          // B-frag lane offset within a 1 KB frag
  // prologue: stage chunk 0
  {
    const ushort_t* g = encC + fr0 * 512 + lane * 8;
    #pragma unroll
    for (int q = 0; q < 4; ++q) dma16(g + q * 512, &stage[0][(fr0 + q) * 512]);
  }
  float tj[8];
  if (p == 0) {
    float4 a = *(const float4*)(etime + base + kg * 8);
    float4 c = *(const float4*)(etime + base + kg * 8 + 4);
    tj[0] = a.x; tj[1] = a.y; tj[2] = a.z; tj[3] = a.w;
    tj[4] = c.x; tj[5] = c.y; tj[6] = c.z; tj[7] = c.w;
  }
  for (int ch = 0; ch < nch; ++ch) {
    const int cur = ch & 1;
    const bool mine = ((ch & 1) == p);
    short8 af;
    if (mine) {                              // weights for my tile x this chunk
      const int j0 = ch * 32 + kg * 8;
      #pragma unroll
      for (int v = 0; v < 8; ++v) {
        float dt = ti - tj[v];               // >= 0 where unmasked (times sorted)
        float sk = __expf(-dt * dt * il);
        float rg = __builtin_amdgcn_rcpf(__expf((dt * 0.005f - ll) * is2) + 1.0f);
        float w = __expf(sk * (1.5f - rg));  // exp(sk*gate), gate = 1.5 - 1/(e^{2z}+1)
        w = (j0 + v <= i) ? w : 0.0f;        // causal mask
        af[v] = (short)f2bfu(w);
      }
    }
    __syncthreads();                         // implicit full drain = chunk-ch DMA complete
    if (ch + 1 < nch) {                      // stage next chunk; flight overlaps MFMA+weights
      const ushort_t* g = encC + (size_t)(ch + 1) * 8192 + fr0 * 512 + lane * 8;
      #pragma unroll
      for (int q = 0; q < 4; ++q) dma16(g + q * 512, &stage[cur ^ 1][(fr0 + q) * 512]);
      if (((ch + 1) & 1) == p) {             // prefetch tj for my next chunk
        const int j0n = (ch + 1) * 32 + kg * 8;
        float4 a = *(const float4*)(etime + base + j0n);
        float4 c = *(const float4*)(etime + base + j0n + 4);
        tj[0] = a.x; tj[1] = a.y; tj[2] = a.z; tj[3] = a.w;
        tj[4] = c.x; tj[5] = c.y; tj[6] = c.z; tj[7] = c.w;
      }
    }
    if (mine) {
      #pragma unroll
      for (int nt = 0; nt < 16; ++nt) {
        short8 bf = *(const short8*)(&stage[cur][nt * 512 + boff]);
        acc[nt] = __builtin_amdgcn_mfma_f32_16x16x32_bf16(af, bf, acc[nt], 0, 0, 0);
      }
    }
  }
  // ---- cross-parity combine (stage reused as two 16 KB floatx4 regions) ----
  __syncthreads();
  floatx4* reg0 = (floatx4*)&stage[0][0];
  floatx4* reg1 = (floatx4*)&stage[1][0];
  if (wv == 1) {
    #pragma unroll
    for (int nt = 0; nt < 16; ++nt) reg0[nt * 64 + lane] = acc[nt];
  } else if (wv == 3) {
    #pragma unroll
    for (int nt = 0; nt < 16; ++nt) reg1[nt * 64 + lane] = acc[nt];
  }
  __syncthreads();
  if ((wv & 1) == 0) {                       // wv0 -> tile0, wv2 -> tile1
    floatx4* reg = (wv == 0) ? reg0 : reg1;
    #pragma unroll
    for (int nt = 0; nt < 16; ++nt) acc[nt] += reg[nt * 64 + lane];
    // ---- epilogue: layernorm on raw weighted sums (softmax div cancels in LN) ----
    float gl[16], cl[16];
    #pragma unroll
    for (int nt = 0; nt < 16; ++nt) { gl[nt] = gamma[nt * 16 + m]; cl[nt] = beta[nt * 16 + m]; }
    const int q = lane >> 4;
    #pragma unroll
    for (int r = 0; r < 4; ++r) {
      float h[16];
      float sm = 0.0f, sq = 0.0f;
      #pragma unroll
      for (int nt = 0; nt < 16; ++nt) {
        h[nt] = acc[nt][r];
        sm += h[nt]; sq += h[nt] * h[nt];
      }
      #pragma unroll
      for (int off = 1; off < 16; off <<= 1) {
        sm += __shfl_xor(sm, off);
        sq += __shfl_xor(sq, off);
      }
      float mean = sm * (1.0f / 256.0f);
      float var = sq * (1.0f / 256.0f) - mean * mean;
      float rstd = rsqrtf(var + 1e-6f);
      const int row = q * 4 + r;
      ushort_t* dst = hidden_bf + ((size_t)(base + tile * 16 + row)) * DD + m;
      #pragma unroll
      for (int nt = 0; nt < 16; ++nt)
        dst[nt * 16] = f2bfu((h[nt] - mean) * rstd * gl[nt] + cl[nt]);
    }
  }
}

// ---------------- Kernel 3: MFMA generator: 512 blocks x 32 rows; wave = col-quarter ----------------
__global__ __launch_bounds__(256) void k_gen(
    const ushort_t* __restrict__ noise_bf, const ushort_t* __restrict__ hidden_bf,
    const ushort_t* __restrict__ wcat, const float* __restrict__ wout,
    const float* __restrict__ bout, float* __restrict__ out)
{
  __shared__ float pbuf[4][2][16];
  const int tid = threadIdx.x;
  const int lane = tid & 63, wv = tid >> 6;  // wv = col-quarter
  const int m = lane & 15, kg = lane >> 4;
  const int r0 = blockIdx.x * 32 + m;
  const ushort_t* __restrict__ an0 = noise_bf + (size_t)r0 * DD;
  const ushort_t* __restrict__ an1 = noise_bf + (size_t)(r0 + 16) * DD;
  const ushort_t* __restrict__ ah0 = hidden_bf + (size_t)r0 * DD;
  const ushort_t* __restrict__ ah1 = hidden_bf + (size_t)(r0 + 16) * DD;
  floatx4 acc[2][4];
  #pragma unroll
  for (int t = 0; t < 2; ++t)
    #pragma unroll
    for (int n = 0; n < 4; ++n) acc[t][n] = (floatx4){0.f, 0.f, 0.f, 0.f};
  const ushort_t* __restrict__ bbase = wcat + ((size_t)(wv * 4) * 16 + m) * 512 + kg * 8;
  #pragma unroll
  for (int ks = 0; ks < 16; ++ks) {          // K = 512 in steps of 32
    const int koff = (ks & 7) * 32 + kg * 8;
    short8 a0 = *(const short8*)(((ks < 8) ? an0 : ah0) + koff);
    short8 a1 = *(const short8*)(((ks < 8) ? an1 : ah1) + koff);
    const ushort_t* bp = bbase + ks * 32;
    #pragma unroll
    for (int n = 0; n < 4; ++n) {
      short8 bf = *(const short8*)(bp + (size_t)n * 8192);   // col = (wv*4+n)*16+m
      acc[0][n] = __builtin_amdgcn_mfma_f32_16x16x32_bf16(a0, bf, acc[0][n], 0, 0, 0);
      acc[1][n] = __builtin_amdgcn_mfma_f32_16x16x32_bf16(a1, bf, acc[1][n], 0, 0, 0);
    }
  }
  float wo_l[4];
  #pragma unroll
  for (int n = 0; n < 4; ++n) wo_l[n] = wout[(wv * 4 + n) * 16 + m];
  #pragma unroll
  for (int t = 0; t < 2; ++t) {
    #pragma unroll
    for (int r4 = 0; r4 < 4; ++r4) {
      float p = 0.0f;
      #pragma unroll
      for (int n = 0; n < 4; ++n) p += fmaxf(acc[t][n][r4], 0.0f) * wo_l[n];
      #pragma unroll
      for (int off = 1; off < 16; off <<= 1) p += __shfl_xor(p, off);
      if (m == 0) pbuf[wv][t][kg * 4 + r4] = p;
    }
  }
  __syncthreads();
  if (tid < 32) {
    int t = tid >> 4, rr = tid & 15;
    float x = pbuf[0][t][rr] + pbuf[1][t][rr] + pbuf[2][t][rr] + pbuf[3][t][rr] + bout[0];
    float sp = (x > 15.0f) ? x : log1pf(__expf(x));
    out[blockIdx.x * 32 + t * 16 + rr] = sp;
  }
}

extern "C" void kernel_launch(void* const* d_in, const int* in_sizes, int n_in,
                              void* d_out, int out_size, void* d_ws, size_t ws_size,
                              hipStream_t stream) {
  const int*   etype = (const int*)d_in[0];
  const float* etime = (const float*)d_in[1];
  const float* embw  = (const float*)d_in[2];
  const float* gatew = (const float*)d_in[3];
  const float* gateb = (const float*)d_in[4];
  const float* kerw  = (const float*)d_in[5];
  const float* kerb  = (const float*)d_in[6];
  const float* gamma = (const float*)d_in[7];
  const float* beta  = (const float*)d_in[8];
  const float* wi    = (const float*)d_in[9];   // gen_input_w
  const float* wn    = (const float*)d_in[10];  // gen_noise_w
  const float* wo    = (const float*)d_in[11];  // gen_out_w
  const float* bo    = (const float*)d_in[12];  // gen_out_b
  const float* noise = (const float*)d_in[13];
  float* out = (float*)d_out;

  char* w8 = (char*)d_ws;
  float* ptable       = (float*)(w8);                             // 32 B
  ushort_t* enc_bf    = (ushort_t*)(w8 + 262144);                 // 8 MB
  ushort_t* hidden_bf = (ushort_t*)(w8 + 262144 + 8388608);       // 8 MB
  ushort_t* noise_bf  = (ushort_t*)(w8 + 262144 + 2 * 8388608);   // 8 MB
  ushort_t* wcat      = (ushort_t*)(w8 + 262144 + 3 * 8388608);   // 256 KB

  k_prep<<<4737, 256, 0, stream>>>(etype, etime, embw, gatew, gateb, kerw, kerb,
                                   noise, wn, wi, enc_bf, noise_bf, wcat, ptable);
  k_attn<<<512, 256, 0, stream>>>(enc_bf, etime, etype, ptable,
                                  gamma, beta, hidden_bf);
  k_gen<<<512, 256, 0, stream>>>(noise_bf, hidden_bf, wcat, wo, bo, out);
}

// Round 9
// 163.545 us; speedup vs baseline: 1.1199x; 1.1199x over previous
//
#include <hip/hip_runtime.h>
#include <hip/hip_bf16.h>

#define BD 8
#define LD 2048
#define DD 256

typedef unsigned short ushort_t;
typedef __attribute__((ext_vector_type(8))) short short8;
typedef __attribute__((ext_vector_type(4))) float floatx4;

__device__ __forceinline__ ushort_t f2bfu(float x) {
  __hip_bfloat16 h = __float2bfloat16(x);
  return *reinterpret_cast<ushort_t*>(&h);
}

// async global->LDS DMA, 16 B per lane; LDS dest = wave-uniform base + lane*16
__device__ __forceinline__ void dma16(const ushort_t* g, ushort_t* l) {
  __builtin_amdgcn_global_load_lds(
      (const __attribute__((address_space(1))) unsigned int*)g,
      (__attribute__((address_space(3))) unsigned int*)l,
      16, 0, 0);
}

// s_waitcnt immediates (gfx9 encoding: vmcnt lo[3:0], expcnt[6:4], lgkmcnt[11:8], vmcnt hi[15:14])
#define WAIT_VM0  0x0F70   // vmcnt(0)
#define WAIT_VM8  0x0F78   // vmcnt(8)
#define WAIT_VM10 0x0F7A   // vmcnt(10)
#define WAIT_LGKM 0xC07F   // lgkmcnt(0)

// accurate sin/cos for args up to ~200 rad: one Cody-Waite step, then hw trig
__device__ __forceinline__ float sin_acc(float a) {
  float k = rintf(a * 0.15915494f);
  float r = __builtin_fmaf(-k, 6.2831855f, a);
  r = __builtin_fmaf(-k, -1.7484555e-7f, r);
  return __sinf(r);
}
__device__ __forceinline__ float cos_acc(float a) {
  float k = rintf(a * 0.15915494f);
  float r = __builtin_fmaf(-k, 6.2831855f, a);
  r = __builtin_fmaf(-k, -1.7484555e-7f, r);
  return __cosf(r);
}

// ---------------- Kernel 1: FUSED prep (cast + enc + per-type dots) ----------------
__global__ __launch_bounds__(256) void k_prep(
    const int* __restrict__ etype, const float* __restrict__ etime,
    const float* __restrict__ embw, const float* __restrict__ gatew,
    const float* __restrict__ gateb, const float* __restrict__ kerw,
    const float* __restrict__ kerb, const float* __restrict__ noise,
    const float* __restrict__ wn, const float* __restrict__ wi,
    ushort_t* __restrict__ enc_bf, ushort_t* __restrict__ noise_bf,
    ushort_t* __restrict__ wcat, float* __restrict__ ptable)
{
  const int bk = blockIdx.x;
  const int tid = threadIdx.x;
  if (bk < 4224) {                           // ---- cast ----
    int idx = bk * 256 + tid;                // float4 index
    if (idx < 1048576) {
      float4 f = ((const float4*)noise)[idx];
      ushort4 u;
      u.x = f2bfu(f.x); u.y = f2bfu(f.y); u.z = f2bfu(f.z); u.w = f2bfu(f.w);
      *(ushort4*)(noise_bf + (size_t)idx * 4) = u;
    } else {
      int p = idx - 1048576;                 // 0..32767
      int c = p >> 7;
      int k = (p & 127) * 4;
      const float* src = (k < 256) ? (wn + c * 256 + k) : (wi + c * 256 + (k - 256));
      float4 f = *(const float4*)src;
      ushort4 u;
      u.x = f2bfu(f.x); u.y = f2bfu(f.y); u.z = f2bfu(f.z); u.w = f2bfu(f.w);
      // B-frag-native: frag (c>>4)*16 + (k>>5), lane slot (c&15)*32 + (k&31)
      *(ushort4*)(wcat + (((size_t)(c >> 4) * 16 + (k >> 5)) * 512)
                       + (c & 15) * 32 + (k & 31)) = u;
    }
  } else if (bk < 4736) {                    // ---- enc ----
    int ebk = bk - 4224;                     // 0..511 : b = ebk>>6, ch = ebk&63
    __shared__ float ts[32];
    if (tid < 32) ts[tid] = etime[(ebk >> 6) * LD + (ebk & 63) * 32 + tid];
    __syncthreads();
    uint4* dst = (uint4*)(enc_bf + (size_t)ebk * 8192);
    const int jb = (tid & 3) * 8;
    #pragma unroll
    for (int jblk = 0; jblk < 4; ++jblk) {
      int d = jblk * 64 + (tid >> 2);
      float freq = __expf(-0.07195578416f * (float)d);   // 10000^(-2d/256)
      unsigned int pk[4];
      #pragma unroll
      for (int p = 0; p < 4; ++p) {
        float a0 = ts[jb + 2 * p] * freq;
        float a1 = ts[jb + 2 * p + 1] * freq;
        float v0 = (d & 1) ? cos_acc(a0) : sin_acc(a0);
        float v1 = (d & 1) ? cos_acc(a1) : sin_acc(a1);
        pk[p] = (unsigned int)f2bfu(v0) | ((unsigned int)f2bfu(v1) << 16);
      }
      dst[jblk * 256 + tid] = make_uint4(pk[0], pk[1], pk[2], pk[3]);
    }
  } else {                                   // ---- dots ----
    __shared__ float red[4][3];
    int lane = tid & 63, wvi = tid >> 6;
    for (int ty = 0; ty < 2; ++ty) {
      float te = embw[ty * DD + tid] * 16.0f;   // * sqrt(256)
      float p1 = te * kerw[tid];
      float p2 = te * gatew[tid];
      float p3 = te * gatew[DD + tid];
      #pragma unroll
      for (int off = 32; off > 0; off >>= 1) {
        p1 += __shfl_xor(p1, off);
        p2 += __shfl_xor(p2, off);
        p3 += __shfl_xor(p3, off);
      }
      if (lane == 0) { red[wvi][0] = p1; red[wvi][1] = p2; red[wvi][2] = p3; }
      __syncthreads();
      if (tid == 0) {
        float s1 = red[0][0] + red[1][0] + red[2][0] + red[3][0] + kerb[0];
        float s2 = red[0][1] + red[1][1] + red[2][1] + red[3][1] + gateb[0];
        float s3 = red[0][2] + red[1][2] + red[2][2] + red[3][2] + gateb[1];
        float z = 0.2f * s1;
        float sp = (z > 15.0f) ? z : log1pf(__expf(z));
        float ls = 5.0f * sp;                // softplus(0.2x)/0.2
        ptable[ty * 4 + 0] = 1.0f / (ls * ls);
        ptable[ty * 4 + 1] = 1.0f / (1.0f + __expf(-s2));
        float s = 1.0f / (1.0f + __expf(-s3));
        ptable[ty * 4 + 2] = 1.0f / s;
      }
      __syncthreads();
    }
  }
}

// ---------------- Kernel 2: MFMA causal gated attention + layernorm ----------------
// 1024 blocks (8 b x 128 tiles, big-first, XCD-pinned), 128 threads = 2 waves.
// Waves parity-split the chunk list. Each wave owns a private 2x8 KB double buffer
// and streams chunks with PARTIAL vmcnt waits so >=8 DMAs stay in flight at all
// times (no full drain, no cross-wave barrier until the final combine).
__global__ __launch_bounds__(128) void k_attn(
    const ushort_t* __restrict__ enc_bf, const float* __restrict__ etime,
    const int* __restrict__ etype, const float* __restrict__ ptable,
    const float* __restrict__ gamma, const float* __restrict__ beta,
    ushort_t* __restrict__ hidden_bf)
{
  __shared__ __align__(16) ushort_t stage[2][2][4096];   // [wave][buf][8 KB] = 32 KB
  const int tid = threadIdx.x;
  const int lane = tid & 63, wv = tid >> 6;  // wv = chunk parity
  const int bk = blockIdx.x;
  const int b = bk & 7;                      // block->XCD pinning for enc L2 locality
  const int tl = 127 - (bk >> 3);            // big tiles first
  const int base = b * LD;
  const int m = lane & 15, kg = lane >> 4;
  const int i = tl * 16 + m;                 // this lane's A-row
  const float ti = etime[base + i];
  const int ty = etype[base + i];
  const float il = ptable[ty * 4 + 0];
  const float ll = ptable[ty * 4 + 1];
  const float is2 = 2.0f * ptable[ty * 4 + 2];
  floatx4 acc[16];
  #pragma unroll
  for (int nt = 0; nt < 16; ++nt) acc[nt] = (floatx4){0.f, 0.f, 0.f, 0.f};
  const int nch = tl / 2 + 1;
  const int myn = (nch > wv) ? ((nch - wv + 1) >> 1) : 0;
  const ushort_t* __restrict__ encC = enc_bf + (size_t)(b * 64) * 8192;
  const int boff = m * 32 + kg * 8;          // lane slot within a 1 KB frag
  ushort_t* bufA = &stage[wv][0][0];
  ushort_t* bufB = &stage[wv][1][0];

  if (myn > 0) {
    // ---- prologue: chunk wv fully issued + weights computed ----
    const int c0 = wv;
    float4 ta = *(const float4*)(etime + base + c0 * 32 + kg * 8);
    float4 tc = *(const float4*)(etime + base + c0 * 32 + kg * 8 + 4);
    {
      const ushort_t* g = encC + (size_t)c0 * 8192 + lane * 8;
      #pragma unroll
      for (int q = 0; q < 8; ++q) dma16(g + q * 512, bufA + q * 512);
      #pragma unroll
      for (int q = 0; q < 8; ++q) dma16(g + (q + 8) * 512, bufB + q * 512);
    }
    float tj[8] = {ta.x, ta.y, ta.z, ta.w, tc.x, tc.y, tc.z, tc.w};
    short8 af;
    {
      const int j0 = c0 * 32 + kg * 8;
      #pragma unroll
      for (int v = 0; v < 8; ++v) {
        float dt = ti - tj[v];
        float sk = __expf(-dt * dt * il);
        float rg = __builtin_amdgcn_rcpf(__expf((dt * 0.005f - ll) * is2) + 1.0f);
        float w = __expf(sk * (1.5f - rg));
        w = (j0 + v <= i) ? w : 0.0f;
        af[v] = (short)f2bfu(w);
      }
    }
    // ---- steady-state: >=8 DMAs always outstanding ----
    for (int idx = 0; idx < myn; ++idx) {
      const int ch = wv + 2 * idx;
      const bool more = (idx + 1 < myn);
      const int cn = more ? (ch + 2) : wv;   // clamp keeps waitcnt arithmetic constant
      __builtin_amdgcn_s_waitcnt(WAIT_VM8);            // half A (nt 0..7) landed
      #pragma unroll
      for (int q = 0; q < 8; ++q) {
        short8 bf = *(const short8*)(bufA + q * 512 + boff);
        acc[q] = __builtin_amdgcn_mfma_f32_16x16x32_bf16(af, bf, acc[q], 0, 0, 0);
      }
      float4 na = *(const float4*)(etime + base + cn * 32 + kg * 8);   // 2 tj loads
      float4 nc = *(const float4*)(etime + base + cn * 32 + kg * 8 + 4);
      __builtin_amdgcn_s_waitcnt(WAIT_LGKM);           // A's ds_reads retired
      {
        const ushort_t* g = encC + (size_t)cn * 8192 + lane * 8;
        #pragma unroll
        for (int q = 0; q < 8; ++q) dma16(g + q * 512, bufA + q * 512);
      }
      __builtin_amdgcn_s_waitcnt(WAIT_VM10);           // half B landed (tj+A' in flight)
      #pragma unroll
      for (int q = 0; q < 8; ++q) {
        short8 bf = *(const short8*)(bufB + q * 512 + boff);
        acc[8 + q] = __builtin_amdgcn_mfma_f32_16x16x32_bf16(af, bf, acc[8 + q], 0, 0, 0);
      }
      __builtin_amdgcn_s_waitcnt(WAIT_LGKM);           // B's ds_reads retired
      {
        const ushort_t* g = encC + (size_t)cn * 8192 + lane * 8;
        #pragma unroll
        for (int q = 0; q < 8; ++q) dma16(g + (q + 8) * 512, bufB + q * 512);
      }
      if (more) {                                       // weights for cn (overlaps DMA)
        float ntj[8] = {na.x, na.y, na.z, na.w, nc.x, nc.y, nc.z, nc.w};
        const int j0 = cn * 32 + kg * 8;
        #pragma unroll
        for (int v = 0; v < 8; ++v) {
          float dt = ti - ntj[v];
          float sk = __expf(-dt * dt * il);
          float rg = __builtin_amdgcn_rcpf(__expf((dt * 0.005f - ll) * is2) + 1.0f);
          float w = __expf(sk * (1.5f - rg));
          w = (j0 + v <= i) ? w : 0.0f;
          af[v] = (short)f2bfu(w);
        }
      }
    }
  }
  // ---- cross-parity combine (syncthreads drains all outstanding DMA) ----
  __syncthreads();
  floatx4* reg = (floatx4*)&stage[0][0][0];   // 16 KB alias
  if (wv == 1) {
    #pragma unroll
    for (int nt = 0; nt < 16; ++nt) reg[nt * 64 + lane] = acc[nt];
  }
  __syncthreads();
  if (wv == 0) {
    #pragma unroll
    for (int nt = 0; nt < 16; ++nt) acc[nt] += reg[nt * 64 + lane];
    // ---- epilogue: layernorm on raw weighted sums (softmax div cancels in LN) ----
    float gl[16], cl[16];
    #pragma unroll
    for (int nt = 0; nt < 16; ++nt) { gl[nt] = gamma[nt * 16 + m]; cl[nt] = beta[nt * 16 + m]; }
    const int q = lane >> 4;
    #pragma unroll
    for (int r = 0; r < 4; ++r) {
      float h[16];
      float sm = 0.0f, sq = 0.0f;
      #pragma unroll
      for (int nt = 0; nt < 16; ++nt) {
        h[nt] = acc[nt][r];
        sm += h[nt]; sq += h[nt] * h[nt];
      }
      #pragma unroll
      for (int off = 1; off < 16; off <<= 1) {
        sm += __shfl_xor(sm, off);
        sq += __shfl_xor(sq, off);
      }
      float mean = sm * (1.0f / 256.0f);
      float var = sq * (1.0f / 256.0f) - mean * mean;
      float rstd = rsqrtf(var + 1e-6f);
      const int row = q * 4 + r;
      ushort_t* dst = hidden_bf + ((size_t)(base + tl * 16 + row)) * DD + m;
      #pragma unroll
      for (int nt = 0; nt < 16; ++nt)
        dst[nt * 16] = f2bfu((h[nt] - mean) * rstd * gl[nt] + cl[nt]);
    }
  }
}

// ---------------- Kernel 3: MFMA generator: 512 blocks x 32 rows; wave = col-quarter ----------------
// wcat is B-frag-native: frag (col>>4)*16 + kchunk, lane slot (col&15)*32 + (k&31).
__global__ __launch_bounds__(256) void k_gen(
    const ushort_t* __restrict__ noise_bf, const ushort_t* __restrict__ hidden_bf,
    const ushort_t* __restrict__ wcat, const float* __restrict__ wout,
    const float* __restrict__ bout, float* __restrict__ out)
{
  __shared__ float pbuf[4][2][16];
  const int tid = threadIdx.x;
  const int lane = tid & 63, wv = tid >> 6;  // wv = col-quarter
  const int m = lane & 15, kg = lane >> 4;
  const int r0 = blockIdx.x * 32 + m;
  const ushort_t* __restrict__ an0 = noise_bf + (size_t)r0 * DD;
  const ushort_t* __restrict__ an1 = noise_bf + (size_t)(r0 + 16) * DD;
  const ushort_t* __restrict__ ah0 = hidden_bf + (size_t)r0 * DD;
  const ushort_t* __restrict__ ah1 = hidden_bf + (size_t)(r0 + 16) * DD;
  floatx4 acc[2][4];
  #pragma unroll
  for (int t = 0; t < 2; ++t)
    #pragma unroll
    for (int n = 0; n < 4; ++n) acc[t][n] = (floatx4){0.f, 0.f, 0.f, 0.f};
  const int slot = m * 32 + kg * 8;
  #pragma unroll
  for (int ks = 0; ks < 16; ++ks) {          // K = 512 in steps of 32
    const int koff = (ks & 7) * 32 + kg * 8;
    short8 a0 = *(const short8*)(((ks < 8) ? an0 : ah0) + koff);
    short8 a1 = *(const short8*)(((ks < 8) ? an1 : ah1) + koff);
    #pragma unroll
    for (int n = 0; n < 4; ++n) {
      const ushort_t* bp = wcat + ((size_t)(wv * 4 + n) * 16 + ks) * 512 + slot;
      short8 bf = *(const short8*)bp;        // contiguous 1 KB per wave
      acc[0][n] = __builtin_amdgcn_mfma_f32_16x16x32_bf16(a0, bf, acc[0][n], 0, 0, 0);
      acc[1][n] = __builtin_amdgcn_mfma_f32_16x16x32_bf16(a1, bf, acc[1][n], 0, 0, 0);
    }
  }
  float wo_l[4];
  #pragma unroll
  for (int n = 0; n < 4; ++n) wo_l[n] = wout[(wv * 4 + n) * 16 + m];
  #pragma unroll
  for (int t = 0; t < 2; ++t) {
    #pragma unroll
    for (int r4 = 0; r4 < 4; ++r4) {
      float p = 0.0f;
      #pragma unroll
      for (int n = 0; n < 4; ++n) p += fmaxf(acc[t][n][r4], 0.0f) * wo_l[n];
      #pragma unroll
      for (int off = 1; off < 16; off <<= 1) p += __shfl_xor(p, off);
      if (m == 0) pbuf[wv][t][kg * 4 + r4] = p;
    }
  }
  __syncthreads();
  if (tid < 32) {
    int t = tid >> 4, rr = tid & 15;
    float x = pbuf[0][t][rr] + pbuf[1][t][rr] + pbuf[2][t][rr] + pbuf[3][t][rr] + bout[0];
    float sp = (x > 15.0f) ? x : log1pf(__expf(x));
    out[blockIdx.x * 32 + t * 16 + rr] = sp;
  }
}

extern "C" void kernel_launch(void* const* d_in, const int* in_sizes, int n_in,
                              void* d_out, int out_size, void* d_ws, size_t ws_size,
                              hipStream_t stream) {
  const int*   etype = (const int*)d_in[0];
  const float* etime = (const float*)d_in[1];
  const float* embw  = (const float*)d_in[2];
  const float* gatew = (const float*)d_in[3];
  const float* gateb = (const float*)d_in[4];
  const float* kerw  = (const float*)d_in[5];
  const float* kerb  = (const float*)d_in[6];
  const float* gamma = (const float*)d_in[7];
  const float* beta  = (const float*)d_in[8];
  const float* wi    = (const float*)d_in[9];   // gen_input_w
  const float* wn    = (const float*)d_in[10];  // gen_noise_w
  const float* wo    = (const float*)d_in[11];  // gen_out_w
  const float* bo    = (const float*)d_in[12];  // gen_out_b
  const float* noise = (const float*)d_in[13];
  float* out = (float*)d_out;

  char* w8 = (char*)d_ws;
  float* ptable       = (float*)(w8);                             // 32 B
  ushort_t* enc_bf    = (ushort_t*)(w8 + 262144);                 // 8 MB
  ushort_t* hidden_bf = (ushort_t*)(w8 + 262144 + 8388608);       // 8 MB
  ushort_t* noise_bf  = (ushort_t*)(w8 + 262144 + 2 * 8388608);   // 8 MB
  ushort_t* wcat      = (ushort_t*)(w8 + 262144 + 3 * 8388608);   // 256 KB

  k_prep<<<4737, 256, 0, stream>>>(etype, etime, embw, gatew, gateb, kerw, kerb,
                                   noise, wn, wi, enc_bf, noise_bf, wcat, ptable);
  k_attn<<<1024, 128, 0, stream>>>(enc_bf, etime, etype, ptable,
                                   gamma, beta, hidden_bf);
  k_gen<<<512, 256, 0, stream>>>(noise_bf, hidden_bf, wcat, wo, bo, out);
}